// Round 6
// baseline (409.902 us; speedup 1.0000x reference)
//
#include <hip/hip_runtime.h>

// ---------------------------------------------------------------------------
// SpatialTransformerPyramid2d fused, round 6.
// N=64, c=32, H=W=128, outdims=4096, SCALE_N=4.
//
// Identity: sample(hi_{j-1}) = bilin(img_{j-1}) - 4*stencil_{j-1}(lo_j);
// level-j bilinear taps lie inside the 3-tap stencil frame -> one 3x4 patch
// per level serves both terms.  Per (out,ch): 4 global taps + 4x12 LDS taps.
//
// Round-6 change (occupancy attack): 512-thread blocks.
//  - At 64 VGPRs the HW allows 8 waves/SIMD = 32 waves/CU (m69 ladder).
//  - 256-thr blocks were LDS-capped at 7 blocks/CU (21.8 KB pyramid floor)
//    and the 2048-grid dispatched 7+1 -> measured ~13 waves/CU.
//  - 512-thr: 4 blocks/CU x 8 waves = 32 waves/CU, LDS 4x22.7 = 91 KB OK,
//    grid 2048 = exactly 2 uniform rounds of 4 blocks/CU (tail-free).
//  - __launch_bounds__(512,4): VGPR cap 256/4 = 64 = r5's natural usage.
//    (Measured allocator rule: cap = floor(256/waves_per_eu); forcing far
//    below natural usage spills GBs -- (256,6)/(512,6) gave 40 regs + 1.6 GB
//    scratch traffic.  64 matches natural, so no spill expected.)
//
// Weight table: SoA, float4 component m for `out` at W[m*4096+out] -> every
// wave-load is 1 KB contiguous.
// ---------------------------------------------------------------------------

#define P1 66
#define P2 34
#define P3 18
#define P4 10
#define OFF_LO1 0                      // 64*66 = 4224
#define OFF_LO2 4224                   // 32*34 = 1088
#define OFF_LO3 5312                   // 16*18 = 288
#define OFF_LO4 5600                   // 8*10  = 80
#define SLOT    5680                   // floats per channel (22720 B)

#define G_A 0.0613609f
#define G_B 0.2447700f
#define G_C 0.3877386f

static __device__ __forceinline__ float clampf(float v, float lo, float hi) {
    return fminf(fmaxf(v, lo), hi);
}
static __device__ __forceinline__ int imin(int a, int b) { return a < b ? a : b; }
static __device__ __forceinline__ int imax(int a, int b) { return a > b ? a : b; }

__global__ void init_out_kernel(const float* __restrict__ bias, float* __restrict__ y) {
    int i = blockIdx.x * blockDim.x + threadIdx.x;
    y[i] = bias[i & 4095];
}

// ---------------------------------------------------------------------------
// SoA weight table: float4 component m for point `out` at ws4[m*4096 + out].
//  m=0 : level-0 bilinear weights w00,w01,w10,w11
//  m=1 : level-0 tap offsets (int bits)
//  m=2+5(j-1)+{0,1,2,3,4} : AX[4], BX[4], AY[3]+pad, BY[3]+pad, rowoffs[3]+pad
// ---------------------------------------------------------------------------
__global__ void weights_kernel(const float* __restrict__ grid, float* __restrict__ ws) {
    int out = blockIdx.x * blockDim.x + threadIdx.x;
    if (out >= 4096) return;
    float xs = clampf(grid[2 * out + 0], -1.f, 1.f);
    float ys = clampf(grid[2 * out + 1], -1.f, 1.f);
    float rec[88];

    // level 0
    float fx = (xs + 1.f) * 64.f - 0.5f;
    float fy = (ys + 1.f) * 64.f - 0.5f;
    float x0f = floorf(fx), y0f = floorf(fy);
    int x0 = (int)x0f, y0 = (int)y0f;
    float wx = fx - x0f, wy = fy - y0f;
    float ux0 = (x0 >= 0)      ? (1.f - wx) : 0.f;
    float ux1 = (x0 + 1 < 128) ? wx         : 0.f;
    float uy0 = (y0 >= 0)      ? (1.f - wy) : 0.f;
    float uy1 = (y0 + 1 < 128) ? wy         : 0.f;
    int cx0 = imax(x0, 0), cx1 = imin(x0 + 1, 127);
    int cy0 = imax(y0, 0), cy1 = imin(y0 + 1, 127);
    rec[0] = ux0 * uy0; rec[1] = ux1 * uy0; rec[2] = ux0 * uy1; rec[3] = ux1 * uy1;
    rec[4] = __int_as_float(cy0 * 128 + cx0);
    rec[5] = __int_as_float(cy0 * 128 + cx1);
    rec[6] = __int_as_float(cy1 * 128 + cx0);
    rec[7] = __int_as_float(cy1 * 128 + cx1);

    int   x0p = x0, y0p = y0;
    float ux0p = ux0, ux1p = ux1, uy0p = uy0, uy1p = uy1;

    const int offs[4]    = {OFF_LO1, OFF_LO2, OFF_LO3, OFF_LO4};
    const int strides[4] = {P1, P2, P3, P4};

    for (int j = 1; j <= 4; ++j) {
        const int Wj = 128 >> j, Pj = strides[j - 1], off = offs[j - 1];

        // a-weights (3-tap transposed-conv stencil from level j-1 corners)
        int qx; float a0, a1, a2;
        if (x0p & 1) { qx = (x0p - 1) >> 1;
            a0 = G_B * ux0p + G_A * ux1p; a1 = G_B * ux0p + G_C * ux1p; a2 = G_A * ux1p; }
        else         { qx = (x0p >> 1) - 1;
            a0 = G_A * ux0p; a1 = G_C * ux0p + G_B * ux1p; a2 = G_A * ux0p + G_B * ux1p; }
        int qy; float e0, e1, e2;
        if (y0p & 1) { qy = (y0p - 1) >> 1;
            e0 = G_B * uy0p + G_A * uy1p; e1 = G_B * uy0p + G_C * uy1p; e2 = G_A * uy1p; }
        else         { qy = (y0p >> 1) - 1;
            e0 = G_A * uy0p; e1 = G_C * uy0p + G_B * uy1p; e2 = G_A * uy0p + G_B * uy1p; }

        // level-j bilinear
        float half = (float)(Wj >> 1);
        float fxj = (xs + 1.f) * half - 0.5f;
        float fyj = (ys + 1.f) * half - 0.5f;
        float x0jf = floorf(fxj), y0jf = floorf(fyj);
        int x0j = (int)x0jf, y0j = (int)y0jf;
        float wxj = fxj - x0jf, wyj = fyj - y0jf;
        float ux0j = (x0j >= 0)     ? (1.f - wxj) : 0.f;
        float ux1j = (x0j + 1 < Wj) ? wxj         : 0.f;
        float uy0j = (y0j >= 0)     ? (1.f - wyj) : 0.f;
        float uy1j = (y0j + 1 < Wj) ? wyj         : 0.f;

        // even 4-wide x frame covering all in-bounds taps
        int bxb = qx & ~1;
        bxb = imin(imax(bxb, 0), Wj - 4);

        float* L = rec + 8 + (j - 1) * 20;
#pragma unroll
        for (int t = 0; t < 4; ++t) {
            int col = bxb + t;
            int s = col - qx;
            float av = (s == 0) ? a0 : (s == 1) ? a1 : (s == 2) ? a2 : 0.f;
            if (s < 0 || s > 2) av = 0.f;
            int sb = col - x0j;
            float bv = (sb == 0) ? ux0j : (sb == 1) ? ux1j : 0.f;
            L[t] = av;
            L[4 + t] = bv;
        }
#pragma unroll
        for (int t = 0; t < 3; ++t) {
            int row = qy + t;
            bool v = (row >= 0) && (row < Wj);
            float av = (t == 0) ? e0 : (t == 1) ? e1 : e2;
            L[8 + t] = v ? av : 0.f;
            int sb = row - y0j;
            L[12 + t] = (sb == 0) ? uy0j : (sb == 1) ? uy1j : 0.f;
            int rc = imin(imax(row, 0), Wj - 1);
            L[16 + t] = __int_as_float(off + rc * Pj + bxb);
        }
        L[11] = 0.f; L[15] = 0.f; L[19] = 0.f;

        x0p = x0j; y0p = y0j;
        ux0p = ux0j; ux1p = ux1j; uy0p = uy0j; uy1p = uy1j;
    }

    // scatter to SoA
    float4* W = (float4*)ws;
#pragma unroll
    for (int m = 0; m < 22; ++m) {
        W[m * 4096 + out] = make_float4(rec[4 * m], rec[4 * m + 1],
                                        rec[4 * m + 2], rec[4 * m + 3]);
    }
}

// smooth+downsample one point from LDS src (stride, logical S x S, zero pad)
static __device__ __forceinline__ float down_pt_lds(const float* s, int stride, int S,
                                                    int i, int j) {
    const float g1[5] = {G_A, G_B, G_C, G_B, G_A};
    int by = 2 * i - 2, bx = 2 * j - 2;
    float acc = 0.f;
    if (by >= 0 && by + 4 < S && bx >= 0 && bx + 4 < S) {
#pragma unroll
        for (int dy = 0; dy < 5; ++dy) {
            const float* r = s + (by + dy) * stride + bx;
            acc += g1[dy] * (G_A * (r[0] + r[4]) + G_B * (r[1] + r[3]) + G_C * r[2]);
        }
    } else {
#pragma unroll
        for (int dy = 0; dy < 5; ++dy) {
            int yy = by + dy;
            if ((unsigned)yy < (unsigned)S) {
#pragma unroll
                for (int dx = 0; dx < 5; ++dx) {
                    int xx = bx + dx;
                    if ((unsigned)xx < (unsigned)S)
                        acc += g1[dy] * g1[dx] * s[yy * stride + xx];
                }
            }
        }
    }
    return acc;
}

__global__ __launch_bounds__(512, 4) void pyr_sample_kernel(
    const float* __restrict__ x, const float* __restrict__ wrec,
    const float* __restrict__ feat, float* __restrict__ y)
{
    __shared__ float s_lo[SLOT];
    const int tid = threadIdx.x;
    const int n   = blockIdx.x >> 5;   // 64
    const int c   = blockIdx.x & 31;   // 32
    const float* img = x + ((size_t)(n * 32 + c) << 14);

    const float g1[5] = {G_A, G_B, G_C, G_B, G_A};

    // ---- phase 1: lo1 (64x64), runs of 4 adjacent points ------------------
    for (int r = tid; r < 1024; r += 512) {
        int i = r >> 4, j0 = (r & 15) << 2;
        int by = 2 * i - 2, bx = 2 * j0 - 2;
        float acc[4] = {0.f, 0.f, 0.f, 0.f};
        if (i >= 1 && i <= 62 && j0 >= 4 && j0 <= 56) {
#pragma unroll
            for (int dy = 0; dy < 5; ++dy) {
                const float* row = img + (by + dy) * 128 + bx;
                float v[11];
#pragma unroll
                for (int t = 0; t < 11; ++t) v[t] = row[t];
                float g = g1[dy];
#pragma unroll
                for (int jj = 0; jj < 4; ++jj) {
                    float h = G_A * (v[2 * jj] + v[2 * jj + 4]) +
                              G_B * (v[2 * jj + 1] + v[2 * jj + 3]) +
                              G_C * v[2 * jj + 2];
                    acc[jj] += g * h;
                }
            }
        } else {
#pragma unroll
            for (int dy = 0; dy < 5; ++dy) {
                int yy = by + dy;
                if ((unsigned)yy < 128u) {
#pragma unroll
                    for (int t = 0; t < 11; ++t) {
                        int xx = bx + t;
                        if ((unsigned)xx < 128u) {
                            float v = img[yy * 128 + xx];
#pragma unroll
                            for (int jj = 0; jj < 4; ++jj) {
                                int dx = t - 2 * jj;
                                if (dx >= 0 && dx <= 4) acc[jj] += g1[dy] * g1[dx] * v;
                            }
                        }
                    }
                }
            }
        }
        int base = OFF_LO1 + i * P1 + j0;   // even (P1 even, j0%4==0)
        *(float2*)&s_lo[base]     = make_float2(acc[0], acc[1]);
        *(float2*)&s_lo[base + 2] = make_float2(acc[2], acc[3]);
    }
    __syncthreads();

    // ---- phase 2: lo2 (32x32) ----
    for (int p = tid; p < 1024; p += 512) {
        int i = p >> 5, j = p & 31;
        s_lo[OFF_LO2 + i * P2 + j] = down_pt_lds(s_lo + OFF_LO1, P1, 64, i, j);
    }
    __syncthreads();

    // ---- phase 3: lo3 (16x16) ----
    if (tid < 256) {
        int i = tid >> 4, j = tid & 15;
        s_lo[OFF_LO3 + i * P3 + j] = down_pt_lds(s_lo + OFF_LO2, P2, 32, i, j);
    }
    __syncthreads();

    // ---- phase 4: lo4 (8x8) ----
    if (tid < 64) {
        int i = tid >> 3, j = tid & 7;
        s_lo[OFF_LO4 + i * P4 + j] = down_pt_lds(s_lo + OFF_LO3, P3, 16, i, j);
    }
    __syncthreads();

    // ---- phase 5: sample + contract using SoA precomputed weights ---------
    const float4* W = (const float4*)wrec;
    float* yrow = y + ((size_t)n << 12);
    for (int out = tid; out < 4096; out += 512) {
        float4 w0 = W[out];                 // m=0
        float4 t1 = W[4096 + out];          // m=1
        int o00 = __float_as_int(t1.x), o01 = __float_as_int(t1.y);
        int o10 = __float_as_int(t1.z), o11 = __float_as_int(t1.w);

        float f_prev = feat[((size_t)c << 12) + out];
        float v0 = w0.x * img[o00] + w0.y * img[o01] + w0.z * img[o10] + w0.w * img[o11];
        float acc = f_prev * v0;

#pragma unroll
        for (int j = 1; j <= 4; ++j) {
            const int mb = (2 + 5 * (j - 1)) * 4096 + out;
            const float4 axw = W[mb];
            const float4 bxw = W[mb + 4096];
            const float4 ayw = W[mb + 2 * 4096];
            const float4 byw = W[mb + 3 * 4096];
            const float4 rrf = W[mb + 4 * 4096];
            int r0 = __float_as_int(rrf.x);
            int r1 = __float_as_int(rrf.y);
            int r2 = __float_as_int(rrf.z);

            float f_cur = feat[((size_t)(j * 32 + c) << 12) + out];

            float2 p0a = *(const float2*)&s_lo[r0];
            float2 p0b = *(const float2*)&s_lo[r0 + 2];
            float2 p1a = *(const float2*)&s_lo[r1];
            float2 p1b = *(const float2*)&s_lo[r1 + 2];
            float2 p2a = *(const float2*)&s_lo[r2];
            float2 p2b = *(const float2*)&s_lo[r2 + 2];
            float ra0 = axw.x * p0a.x + axw.y * p0a.y + axw.z * p0b.x + axw.w * p0b.y;
            float ra1 = axw.x * p1a.x + axw.y * p1a.y + axw.z * p1b.x + axw.w * p1b.y;
            float ra2 = axw.x * p2a.x + axw.y * p2a.y + axw.z * p2b.x + axw.w * p2b.y;
            float rb0 = bxw.x * p0a.x + bxw.y * p0a.y + bxw.z * p0b.x + bxw.w * p0b.y;
            float rb1 = bxw.x * p1a.x + bxw.y * p1a.y + bxw.z * p1b.x + bxw.w * p1b.y;
            float rb2 = bxw.x * p2a.x + bxw.y * p2a.y + bxw.z * p2b.x + bxw.w * p2b.y;
            float sa = ayw.x * ra0 + ayw.y * ra1 + ayw.z * ra2;
            float sb = byw.x * rb0 + byw.y * rb1 + byw.z * rb2;
            acc += f_cur * sb - 4.f * f_prev * sa;
            f_prev = f_cur;
        }
        atomicAdd(&yrow[out], acc);
    }
}

extern "C" void kernel_launch(void* const* d_in, const int* in_sizes, int n_in,
                              void* d_out, int out_size, void* d_ws, size_t ws_size,
                              hipStream_t stream) {
    (void)in_sizes; (void)n_in; (void)ws_size;
    const float* x    = (const float*)d_in[0];
    const float* grid = (const float*)d_in[1];
    const float* feat = (const float*)d_in[2];
    const float* bias = (const float*)d_in[3];
    float* y  = (float*)d_out;
    float* ws = (float*)d_ws;

    weights_kernel<<<16, 256, 0, stream>>>(grid, ws);
    init_out_kernel<<<out_size / 256, 256, 0, stream>>>(bias, y);
    pyr_sample_kernel<<<2048, 512, 0, stream>>>(x, ws, feat, y);
}